// Round 1
// baseline (518.425 us; speedup 1.0000x reference)
//
#include <hip/hip_runtime.h>

#define NN 50000
#define EE 800000
#define DD 128
#define RR 8
#define KSTACK 1152   // (RR+1)*DD

typedef __attribute__((ext_vector_type(8))) short bf16x8;
typedef __attribute__((ext_vector_type(4))) float f32x4;

__device__ inline float bf2f(ushort u) {
    union { uint i; float f; } v; v.i = ((uint)u) << 16; return v.f;
}
__device__ inline ushort f2bf(float f) {
    uint b = __float_as_uint(f);
    uint r = (b + 0x7fffu + ((b >> 16) & 1u)) >> 16;
    return (ushort)r;
}

// Build transposed stacked weight: wT[o][k], k in [0,1152).
// k<1024: W[r=k>>7][i=k&127][o] = sum_b comp[r,b]*basis[b,i,o]; k>=1024: root[k-1024][o].
__global__ void k_build_w(const float* __restrict__ basis, const float* __restrict__ comp,
                          const float* __restrict__ root, ushort* __restrict__ wT) {
    int idx = blockIdx.x * 256 + threadIdx.x;
    if (idx >= DD * KSTACK) return;
    int o = idx / KSTACK;
    int k = idx % KSTACK;
    float val;
    if (k < RR * DD) {
        int r = k >> 7, i = k & 127;
        float s = 0.f;
        #pragma unroll
        for (int b = 0; b < 8; ++b) s += comp[r * 8 + b] * basis[(b * 128 + i) * 128 + o];
        val = s;
    } else {
        val = root[(k - RR * DD) * 128 + o];
    }
    wT[(size_t)o * KSTACK + k] = f2bf(val);
}

__global__ void k_cvt_bf16(const float* __restrict__ x, ushort* __restrict__ xb, int n) {
    int i = blockIdx.x * 256 + threadIdx.x;
    if (i < n) xb[i] = f2bf(x[i]);
}

__global__ void k_hist(const int* __restrict__ ei, const int* __restrict__ et,
                       int* __restrict__ deg_r, int* __restrict__ row_cnt) {
    int e = blockIdx.x * 256 + threadIdx.x;
    if (e < EE) {
        int d = ei[EE + e];
        int t = et[e];
        atomicAdd(&deg_r[d * RR + t], 1);
        atomicAdd(&row_cnt[d], 1);
    }
}

__global__ void k_scan1(const int* __restrict__ cnt, int* __restrict__ bsum, int n) {
    __shared__ int s[256];
    int t = threadIdx.x;
    int i = blockIdx.x * 256 + t;
    s[t] = (i < n) ? cnt[i] : 0;
    __syncthreads();
    for (int o = 128; o > 0; o >>= 1) {
        if (t < o) s[t] += s[t + o];
        __syncthreads();
    }
    if (t == 0) bsum[blockIdx.x] = s[0];
}

__global__ void k_scan2(int* __restrict__ bsum, int nb) {
    __shared__ int s[256];
    int t = threadIdx.x;
    int v = (t < nb) ? bsum[t] : 0;
    s[t] = v;
    __syncthreads();
    for (int o = 1; o < 256; o <<= 1) {
        int u = (t >= o) ? s[t - o] : 0;
        __syncthreads();
        s[t] += u;
        __syncthreads();
    }
    if (t < nb) bsum[t] = s[t] - v;   // exclusive
}

__global__ void k_scan3(const int* __restrict__ cnt, const int* __restrict__ boff,
                        int* __restrict__ ptr, int n) {
    __shared__ int s[256];
    int t = threadIdx.x;
    int i = blockIdx.x * 256 + t;
    int v = (i < n) ? cnt[i] : 0;
    s[t] = v;
    __syncthreads();
    for (int o = 1; o < 256; o <<= 1) {
        int u = (t >= o) ? s[t - o] : 0;
        __syncthreads();
        s[t] += u;
        __syncthreads();
    }
    if (i < n) ptr[i + 1] = boff[blockIdx.x] + s[t];
    if (i == 0) ptr[0] = 0;
}

__global__ void k_scatter(const int* __restrict__ ei, const int* __restrict__ et,
                          const int* __restrict__ row_ptr, int* __restrict__ cursor,
                          int* __restrict__ ekey) {
    int e = blockIdx.x * 256 + threadIdx.x;
    if (e < EE) {
        int s = ei[e], d = ei[EE + e], t = et[e];
        int p = row_ptr[d] + atomicAdd(&cursor[d], 1);
        ekey[p] = (s << 3) | t;
    }
}

// One wave per dst row: accumulate gathered bf16 rows per relation in LDS fp32,
// scale by 1/deg, append self row, write Asum[n][1152] bf16.
__global__ void __launch_bounds__(256) k_agg(const ushort* __restrict__ in,
                                             const int* __restrict__ row_ptr,
                                             const int* __restrict__ ekey,
                                             const int* __restrict__ deg_r,
                                             ushort* __restrict__ asum) {
    __shared__ float lds[4][KSTACK];
    int w = threadIdx.x >> 6, lane = threadIdx.x & 63;
    int n = blockIdx.x * 4 + w;
    if (n >= NN) return;
    float* acc = lds[w];
    #pragma unroll
    for (int j = 0; j < 18; ++j) acc[j * 64 + lane] = 0.f;
    int p0 = row_ptr[n], p1 = row_ptr[n + 1];
    for (int p = p0; p < p1; ++p) {
        int key = ekey[p];
        int t = key & 7, s = key >> 3;
        uint u = *(const uint*)(in + (size_t)s * 128 + lane * 2);
        float* a = acc + t * 128 + lane * 2;
        a[0] += bf2f((ushort)(u & 0xffffu));
        a[1] += bf2f((ushort)(u >> 16));
    }
    ushort* arow = asum + (size_t)n * KSTACK;
    #pragma unroll
    for (int r = 0; r < 8; ++r) {
        float inv = 1.f / (float)max(deg_r[n * RR + r], 1);
        float v0 = acc[r * 128 + lane * 2] * inv;
        float v1 = acc[r * 128 + lane * 2 + 1] * inv;
        uint pk = (uint)f2bf(v0) | ((uint)f2bf(v1) << 16);
        *(uint*)(arow + r * 128 + lane * 2) = pk;
    }
    // self slot = raw input row
    uint su = *(const uint*)(in + (size_t)n * 128 + lane * 2);
    *(uint*)(arow + RR * 128 + lane * 2) = su;
}

// C[n,o] = Asum[n,:] @ Wstack[:,o] + bias[o]; optional relu; bf16 or f32 out.
// Block = 128 threads (2 waves), 64 rows/block (32 rows/wave), all 128 cols.
// A and B fragments load straight from global in native MFMA layout (BT is [col][k]).
__global__ void __launch_bounds__(128) k_gemm(const ushort* __restrict__ A,
                                              const ushort* __restrict__ BT,
                                              const float* __restrict__ bias,
                                              ushort* __restrict__ hout,
                                              float* __restrict__ fout, int M) {
    int wv = threadIdx.x >> 6, lane = threadIdx.x & 63;
    int rowbase = blockIdx.x * 64 + wv * 32;
    int rlo = lane & 15;
    int khi = (lane >> 4) * 8;
    f32x4 acc[2][8];
    #pragma unroll
    for (int f = 0; f < 2; ++f)
        #pragma unroll
        for (int c = 0; c < 8; ++c) acc[f][c] = (f32x4){0.f, 0.f, 0.f, 0.f};

    int r0 = rowbase + rlo;      if (r0 > M - 1) r0 = M - 1;
    int r1 = rowbase + 16 + rlo; if (r1 > M - 1) r1 = M - 1;
    const ushort* a0p = A + (size_t)r0 * KSTACK + khi;
    const ushort* a1p = A + (size_t)r1 * KSTACK + khi;
    const ushort* bp  = BT + (size_t)rlo * KSTACK + khi;

    for (int kk = 0; kk < KSTACK / 32; ++kk) {
        int ko = kk * 32;
        bf16x8 a0 = *(const bf16x8*)(a0p + ko);
        bf16x8 a1 = *(const bf16x8*)(a1p + ko);
        #pragma unroll
        for (int c = 0; c < 8; ++c) {
            bf16x8 b = *(const bf16x8*)(bp + (size_t)c * 16 * KSTACK + ko);
            acc[0][c] = __builtin_amdgcn_mfma_f32_16x16x32_bf16(a0, b, acc[0][c], 0, 0, 0);
            acc[1][c] = __builtin_amdgcn_mfma_f32_16x16x32_bf16(a1, b, acc[1][c], 0, 0, 0);
        }
    }

    int rowoff = (lane >> 4) * 4;
    #pragma unroll
    for (int f = 0; f < 2; ++f) {
        #pragma unroll
        for (int rg = 0; rg < 4; ++rg) {
            int row = rowbase + f * 16 + rowoff + rg;
            if (row >= M) continue;
            #pragma unroll
            for (int c = 0; c < 8; ++c) {
                int col = c * 16 + rlo;
                float v = acc[f][c][rg] + bias[col];
                if (hout) {
                    v = fmaxf(v, 0.f);
                    hout[(size_t)row * 128 + col] = f2bf(v);
                } else {
                    fout[(size_t)row * 128 + col] = v;
                }
            }
        }
    }
}

extern "C" void kernel_launch(void* const* d_in, const int* in_sizes, int n_in,
                              void* d_out, int out_size, void* d_ws, size_t ws_size,
                              hipStream_t stream) {
    const float* x      = (const float*)d_in[0];
    const int*   ei     = (const int*)d_in[1];
    const int*   et     = (const int*)d_in[2];
    const float* basis0 = (const float*)d_in[3];
    const float* comp0  = (const float*)d_in[4];
    const float* root0  = (const float*)d_in[5];
    const float* bias0  = (const float*)d_in[6];
    const float* basis1 = (const float*)d_in[7];
    const float* comp1  = (const float*)d_in[8];
    const float* root1  = (const float*)d_in[9];
    const float* bias1  = (const float*)d_in[10];
    float* out = (float*)d_out;

    char* ws = (char*)d_ws;
    size_t off = 0;
    auto alloc = [&](size_t bytes) -> void* {
        void* p = ws + off;
        off += (bytes + 255) & ~(size_t)255;
        return p;
    };
    int*    deg_r   = (int*)alloc((size_t)NN * RR * 4);
    int*    row_cnt = (int*)alloc((size_t)NN * 4);
    int*    cursor  = (int*)alloc((size_t)NN * 4);
    size_t zero_bytes = off;
    int*    row_ptr = (int*)alloc((size_t)(NN + 1) * 4);
    int*    bsum    = (int*)alloc(256 * 4);
    int*    ekey    = (int*)alloc((size_t)EE * 4);
    ushort* wT0     = (ushort*)alloc((size_t)DD * KSTACK * 2);
    ushort* wT1     = (ushort*)alloc((size_t)DD * KSTACK * 2);
    ushort* xb      = (ushort*)alloc((size_t)NN * DD * 2);
    ushort* h       = (ushort*)alloc((size_t)NN * DD * 2);
    ushort* asum    = (ushort*)alloc((size_t)NN * KSTACK * 2);
    if (off > ws_size) return;  // workspace insufficient — fail loudly via validation

    hipMemsetAsync(d_ws, 0, zero_bytes, stream);

    k_build_w<<<576, 256, 0, stream>>>(basis0, comp0, root0, wT0);
    k_build_w<<<576, 256, 0, stream>>>(basis1, comp1, root1, wT1);
    k_cvt_bf16<<<25000, 256, 0, stream>>>(x, xb, NN * DD);
    k_hist<<<3125, 256, 0, stream>>>(ei, et, deg_r, row_cnt);
    k_scan1<<<196, 256, 0, stream>>>(row_cnt, bsum, NN);
    k_scan2<<<1, 256, 0, stream>>>(bsum, 196);
    k_scan3<<<196, 256, 0, stream>>>(row_cnt, bsum, row_ptr, NN);
    k_scatter<<<3125, 256, 0, stream>>>(ei, et, row_ptr, cursor, ekey);

    int gemm_blocks = (NN + 63) / 64;
    // Layer 0
    k_agg<<<12500, 256, 0, stream>>>(xb, row_ptr, ekey, deg_r, asum);
    k_gemm<<<gemm_blocks, 128, 0, stream>>>(asum, wT0, bias0, h, nullptr, NN);
    // Layer 1
    k_agg<<<12500, 256, 0, stream>>>(h, row_ptr, ekey, deg_r, asum);
    k_gemm<<<gemm_blocks, 128, 0, stream>>>(asum, wT1, bias1, nullptr, out, NN);
}

// Round 2
// 442.443 us; speedup vs baseline: 1.1717x; 1.1717x over previous
//
#include <hip/hip_runtime.h>

#define NN 50000
#define EE 800000
#define DD 128
#define RR 8
#define KSTACK 1152   // (RR+1)*DD
#define NR2 (NN * RR) // 400000
#define RPB 32        // dst rows per fused block
#define LDSROW 1160   // 1152 + 8 bf16 pad (stride 2320B = 4 banks mod 32)

typedef __attribute__((ext_vector_type(8))) short bf16x8;
typedef __attribute__((ext_vector_type(4))) float f32x4;

__device__ inline float bf2f(ushort u) {
    union { uint i; float f; } v; v.i = ((uint)u) << 16; return v.f;
}
__device__ inline ushort f2bf(float f) {
    uint b = __float_as_uint(f);
    uint r = (b + 0x7fffu + ((b >> 16) & 1u)) >> 16;
    return (ushort)r;
}

// wT[o][k], k<1024: sum_b comp[r,b]*basis[b,i,o] (r=k>>7,i=k&127); k>=1024: root[k-1024][o].
__global__ void k_build_w(const float* __restrict__ basis, const float* __restrict__ comp,
                          const float* __restrict__ root, ushort* __restrict__ wT) {
    int idx = blockIdx.x * 256 + threadIdx.x;
    if (idx >= DD * KSTACK) return;
    int o = idx / KSTACK;
    int k = idx % KSTACK;
    float val;
    if (k < RR * DD) {
        int r = k >> 7, i = k & 127;
        float s = 0.f;
        #pragma unroll
        for (int b = 0; b < 8; ++b) s += comp[r * 8 + b] * basis[(b * 128 + i) * 128 + o];
        val = s;
    } else {
        val = root[(k - RR * DD) * 128 + o];
    }
    wT[(size_t)o * KSTACK + k] = f2bf(val);
}

__global__ void k_cvt_bf16(const float* __restrict__ x, ushort* __restrict__ xb, int n) {
    int i = blockIdx.x * 256 + threadIdx.x;
    if (i < n) xb[i] = f2bf(x[i]);
}

__global__ void k_hist(const int* __restrict__ ei, const int* __restrict__ et,
                       int* __restrict__ deg_dr) {
    int e = blockIdx.x * 256 + threadIdx.x;
    if (e < EE) atomicAdd(&deg_dr[ei[EE + e] * RR + et[e]], 1);
}

__global__ void k_scan1(const int* __restrict__ cnt, int* __restrict__ bsum, int n) {
    __shared__ int s[256];
    int t = threadIdx.x;
    int i = blockIdx.x * 256 + t;
    s[t] = (i < n) ? cnt[i] : 0;
    __syncthreads();
    for (int o = 128; o > 0; o >>= 1) {
        if (t < o) s[t] += s[t + o];
        __syncthreads();
    }
    if (t == 0) bsum[blockIdx.x] = s[0];
}

__global__ void k_scan2(int* __restrict__ bsum, int nb) {
    __shared__ int s[256];
    int t = threadIdx.x;
    int v = (t < nb) ? bsum[t] : 0;
    s[t] = v;
    __syncthreads();
    for (int o = 1; o < 256; o <<= 1) {
        int u = (t >= o) ? s[t - o] : 0;
        __syncthreads();
        s[t] += u;
        __syncthreads();
    }
    if (t < nb) bsum[t] = s[t] - v;   // exclusive
}

__global__ void k_scan3(const int* __restrict__ cnt, const int* __restrict__ boff,
                        int* __restrict__ ptr, int n) {
    __shared__ int s[256];
    int t = threadIdx.x;
    int i = blockIdx.x * 256 + t;
    int v = (i < n) ? cnt[i] : 0;
    s[t] = v;
    __syncthreads();
    for (int o = 1; o < 256; o <<= 1) {
        int u = (t >= o) ? s[t - o] : 0;
        __syncthreads();
        s[t] += u;
        __syncthreads();
    }
    if (i < n) ptr[i + 1] = boff[blockIdx.x] + s[t];
    if (i == 0) ptr[0] = 0;
}

__global__ void k_scatter(const int* __restrict__ ei, const int* __restrict__ et,
                          const int* __restrict__ rel_ptr, int* __restrict__ cursor,
                          int* __restrict__ esrc) {
    int e = blockIdx.x * 256 + threadIdx.x;
    if (e < EE) {
        int s = ei[e], d = ei[EE + e], t = et[e];
        int idx = d * RR + t;
        int p = rel_ptr[idx] + atomicAdd(&cursor[idx], 1);
        esrc[p] = s;
    }
}

// Fused layer: block = 32 dst rows, 512 threads (8 waves), 2 blocks/CU.
// Phase 1: per-(row,rel) register accumulation over rel-sorted CSR -> bf16 A-tile in LDS.
// Phase 2: 8 waves x (1 col-tile, 2 row-tiles) MFMA GEMM, A from LDS, B from L2.
__global__ void __launch_bounds__(512, 4) k_fused(
        const ushort* __restrict__ in, const int* __restrict__ rp,
        const int* __restrict__ esrc, const ushort* __restrict__ BT,
        const float* __restrict__ bias, ushort* __restrict__ hout,
        float* __restrict__ fout) {
    __shared__ ushort at[RPB * LDSROW];   // 74240 B
    int wid = threadIdx.x >> 6, lane = threadIdx.x & 63;
    int blockrow = blockIdx.x * RPB;
    int l2 = lane << 1;

    #pragma unroll
    for (int rr = 0; rr < 4; ++rr) {
        int lr = (wid << 2) + rr;
        int n = blockrow + lr;
        ushort* arow = at + lr * LDSROW;
        if (n < NN) {
            int base = n << 3;
            int pb0 = __builtin_amdgcn_readfirstlane(rp[base]);
            #pragma unroll
            for (int t = 0; t < RR; ++t) {
                int p1 = __builtin_amdgcn_readfirstlane(rp[base + t + 1]);
                float a0 = 0.f, a1 = 0.f;
                int p = pb0;
                while (p + 1 < p1) {
                    int s0 = esrc[p], s1 = esrc[p + 1];
                    uint u0 = *(const uint*)(in + (size_t)s0 * DD + l2);
                    uint u1 = *(const uint*)(in + (size_t)s1 * DD + l2);
                    a0 += bf2f((ushort)(u0 & 0xffffu)) + bf2f((ushort)(u1 & 0xffffu));
                    a1 += bf2f((ushort)(u0 >> 16)) + bf2f((ushort)(u1 >> 16));
                    p += 2;
                }
                if (p < p1) {
                    int s0 = esrc[p];
                    uint u0 = *(const uint*)(in + (size_t)s0 * DD + l2);
                    a0 += bf2f((ushort)(u0 & 0xffffu));
                    a1 += bf2f((ushort)(u0 >> 16));
                }
                int deg = p1 - pb0;
                float inv = (deg > 0) ? (1.f / (float)deg) : 1.f;
                uint pk = (uint)f2bf(a0 * inv) | ((uint)f2bf(a1 * inv) << 16);
                *(uint*)(arow + t * DD + l2) = pk;
                pb0 = p1;
            }
            // self (root) slot
            uint su = *(const uint*)(in + (size_t)n * DD + l2);
            *(uint*)(arow + RR * DD + l2) = su;
        } else {
            #pragma unroll
            for (int j = 0; j < 9; ++j) *(uint*)(arow + j * DD + l2) = 0u;
        }
    }
    __syncthreads();

    // Phase 2
    int rlo = lane & 15, khi = (lane >> 4) << 3;
    const ushort* bp  = BT + (size_t)(wid * 16 + rlo) * KSTACK + khi;
    const ushort* a0p = at + rlo * LDSROW + khi;
    const ushort* a1p = at + (16 + rlo) * LDSROW + khi;
    f32x4 acc0 = {0.f, 0.f, 0.f, 0.f}, acc1 = {0.f, 0.f, 0.f, 0.f};
    #pragma unroll 4
    for (int kk = 0; kk < KSTACK / 32; ++kk) {
        int ko = kk * 32;
        bf16x8 b  = *(const bf16x8*)(bp + ko);
        bf16x8 a0 = *(const bf16x8*)(a0p + ko);
        bf16x8 a1 = *(const bf16x8*)(a1p + ko);
        acc0 = __builtin_amdgcn_mfma_f32_16x16x32_bf16(a0, b, acc0, 0, 0, 0);
        acc1 = __builtin_amdgcn_mfma_f32_16x16x32_bf16(a1, b, acc1, 0, 0, 0);
    }
    int col = wid * 16 + rlo;
    float bv = bias[col];
    int rowoff = (lane >> 4) << 2;
    #pragma unroll
    for (int f = 0; f < 2; ++f) {
        f32x4 av = f ? acc1 : acc0;
        #pragma unroll
        for (int rg = 0; rg < 4; ++rg) {
            int row = blockrow + f * 16 + rowoff + rg;
            if (row < NN) {
                float v = av[rg] + bv;
                if (hout) {
                    v = fmaxf(v, 0.f);
                    hout[(size_t)row * DD + col] = f2bf(v);
                } else {
                    fout[(size_t)row * DD + col] = v;
                }
            }
        }
    }
}

extern "C" void kernel_launch(void* const* d_in, const int* in_sizes, int n_in,
                              void* d_out, int out_size, void* d_ws, size_t ws_size,
                              hipStream_t stream) {
    const float* x      = (const float*)d_in[0];
    const int*   ei     = (const int*)d_in[1];
    const int*   et     = (const int*)d_in[2];
    const float* basis0 = (const float*)d_in[3];
    const float* comp0  = (const float*)d_in[4];
    const float* root0  = (const float*)d_in[5];
    const float* bias0  = (const float*)d_in[6];
    const float* basis1 = (const float*)d_in[7];
    const float* comp1  = (const float*)d_in[8];
    const float* root1  = (const float*)d_in[9];
    const float* bias1  = (const float*)d_in[10];
    float* out = (float*)d_out;

    char* ws = (char*)d_ws;
    size_t off = 0;
    auto alloc = [&](size_t bytes) -> void* {
        void* p = ws + off;
        off += (bytes + 255) & ~(size_t)255;
        return p;
    };
    int*    deg_dr  = (int*)alloc((size_t)NR2 * 4);
    int*    cursor  = (int*)alloc((size_t)NR2 * 4);
    size_t zero_bytes = off;
    int*    rel_ptr = (int*)alloc((size_t)(NR2 + 1) * 4);
    int*    bsum1   = (int*)alloc(1600 * 4);
    int*    bsum2   = (int*)alloc(256 * 4);
    int*    bptr1   = (int*)alloc(1600 * 4);
    int*    esrc    = (int*)alloc((size_t)EE * 4);
    ushort* wT0     = (ushort*)alloc((size_t)DD * KSTACK * 2);
    ushort* wT1     = (ushort*)alloc((size_t)DD * KSTACK * 2);
    ushort* xb      = (ushort*)alloc((size_t)NN * DD * 2);
    ushort* h       = (ushort*)alloc((size_t)NN * DD * 2);
    if (off > ws_size) return;

    hipMemsetAsync(d_ws, 0, zero_bytes, stream);

    k_build_w<<<576, 256, 0, stream>>>(basis0, comp0, root0, wT0);
    k_build_w<<<576, 256, 0, stream>>>(basis1, comp1, root1, wT1);
    k_cvt_bf16<<<25000, 256, 0, stream>>>(x, xb, NN * DD);
    k_hist<<<3125, 256, 0, stream>>>(ei, et, deg_dr);

    // 3-level exclusive scan of deg_dr[400000] -> rel_ptr[400001]
    k_scan1<<<1563, 256, 0, stream>>>(deg_dr, bsum1, NR2);
    k_scan1<<<7, 256, 0, stream>>>(bsum1, bsum2, 1563);
    k_scan2<<<1, 256, 0, stream>>>(bsum2, 7);
    k_scan3<<<7, 256, 0, stream>>>(bsum1, bsum2, bptr1, 1563);
    k_scan3<<<1563, 256, 0, stream>>>(deg_dr, bptr1, rel_ptr, NR2);

    k_scatter<<<3125, 256, 0, stream>>>(ei, et, rel_ptr, cursor, esrc);

    int fblocks = (NN + RPB - 1) / RPB;   // 1563
    k_fused<<<fblocks, 512, 0, stream>>>(xb, rel_ptr, esrc, wT0, bias0, h, nullptr);
    k_fused<<<fblocks, 512, 0, stream>>>(h, rel_ptr, esrc, wT1, bias1, nullptr, out);
}